// Round 12
// baseline (59.095 us; speedup 1.0000x reference)
//
#include <hip/hip_runtime.h>
#include <hip/hip_bf16.h>
#include <math.h>

// image: (B=32, D=64, H=64, W=128) f32
// polar_log_depths: (B=32, H=64, W=128, S=64) f32
// outputs: image_polar (B,D,Z=64,W) f32, cell_score (B,W,Z) f32, concat flat.
#define B_ 32
#define D_ 64
#define H_ 64
#define W_ 128
#define S_ 64
#define Z_ 64

typedef __attribute__((ext_vector_type(8))) short bf16x8;
typedef __attribute__((ext_vector_type(4))) float f32x4;

static __device__ __forceinline__ short f2bf(float f) {
    union { __hip_bfloat16 h; short s; } u;
    u.h = __float2bfloat16(f);
    return u.s;
}
static __device__ __forceinline__ float getc(const float4& v, int k) {
    switch (k) { case 0: return v.x; case 1: return v.y; case 2: return v.z; default: return v.w; }
}

// Swizzled byte offset of a 16B column-octet slot in an 8KB [64 rows][128 B] plane.
static __device__ __forceinline__ int swz(int w, int row, int oct) {
    return w * 8192 + row * 128 + (((oct ^ row ^ w) & 7) << 4);
}

struct Regs { float4 ir[4]; float4 pr[4]; };

// Issue the 8 global loads for one (b, w-quad) tile. (R10 phases 1-2.)
static __device__ __forceinline__ void issue_loads(const float* __restrict__ image,
                                                   const float* __restrict__ polar,
                                                   int b, int w0, int t, Regs& r) {
    const int d_im = t >> 4;
    const int h0   = (t & 15) << 2;
#pragma unroll
    for (int k = 0; k < 4; ++k)
        r.ir[k] = *(const float4*)(image + ((size_t)((b * D_ + d_im) * H_ + h0 + k)) * W_ + w0);
    const int q4 = t & 3;
    const int rr = t >> 2;
    const int w_p = rr >> 6, h_p = rr & 63;
    const float* src = polar + ((size_t)((b * H_ + h_p) * W_ + w0 + w_p)) * S_ + q4 * 16;
#pragma unroll
    for (int k = 0; k < 4; ++k)
        r.pr[k] = *(const float4*)(src + k * 4);
}

// cvt + swizzled LDS stores for one tile. (R10 phases 3-4.)
static __device__ __forceinline__ void lds_write(unsigned char* sP, unsigned char* sA,
                                                 int t, const Regs& r) {
    const int d_im = t >> 4;
    const int h0   = (t & 15) << 2;
#pragma unroll
    for (int w = 0; w < 4; ++w) {
        int2 pk;
        pk.x = (f2bf(getc(r.ir[0], w)) & 0xffff) | (f2bf(getc(r.ir[1], w)) << 16);
        pk.y = (f2bf(getc(r.ir[2], w)) & 0xffff) | (f2bf(getc(r.ir[3], w)) << 16);
        *(int2*)(sA + swz(w, d_im, h0 >> 3) + ((h0 & 7) << 1)) = pk;
    }
    const int q4 = t & 3;
    const int rr = t >> 2;
    const int w_p = rr >> 6, h_p = rr & 63;
#pragma unroll
    for (int c = 0; c < 2; ++c) {
        bf16x8 v;
#pragma unroll
        for (int e = 0; e < 8; ++e)
            v[e] = f2bf(getc(r.pr[c * 2 + (e >> 2)], e & 3));
        *(bf16x8*)(sP + swz(w_p, h_p, q4 * 2 + c)) = v;
    }
}

// S-MFMA (register-built Wz) + in-register softmax + cell_score. (R10 phase 5.)
static __device__ __forceinline__ void s_phase(const unsigned char* sP, int b, int w0,
                                               int wS, int zq, int fr, int lg,
                                               float* __restrict__ out_cell,
                                               float ex[4][4], float& inv) {
    const int z = zq * 16 + fr;
    const float posf = (log2f(0.5f + 0.5f * (float)z) + 1.0f) * 10.5f;  // (63/6)
    int i0 = (int)floorf(posf);
    i0 = i0 < 0 ? 0 : (i0 > S_ - 1 ? S_ - 1 : i0);
    const int i1 = (i0 + 1 > S_ - 1) ? (S_ - 1) : (i0 + 1);
    const float wz = posf - (float)i0;

    bf16x8 bw[2];
#pragma unroll
    for (int ks = 0; ks < 2; ++ks)
#pragma unroll
        for (int e = 0; e < 8; ++e) {
            const int s = ks * 32 + lg * 8 + e;
            const float v = (s == i0 ? 1.0f - wz : 0.0f) + (s == i1 ? wz : 0.0f);
            bw[ks][e] = f2bf(v);
        }

    f32x4 sacc[4] = {};
#pragma unroll
    for (int ks = 0; ks < 2; ++ks)
#pragma unroll
        for (int mt = 0; mt < 4; ++mt) {
            const bf16x8 a = *(const bf16x8*)(sP + swz(wS, mt * 16 + fr, ks * 4 + lg));
            sacc[mt] = __builtin_amdgcn_mfma_f32_16x16x32_bf16(a, bw[ks], sacc[mt], 0, 0, 0);
        }

    float ss = 0.0f;
#pragma unroll
    for (int mt = 0; mt < 4; ++mt)
#pragma unroll
        for (int r = 0; r < 4; ++r) {
            const float e = __expf(sacc[mt][r]);
            ex[mt][r] = e;
            ss += e;
        }
    ss += __shfl_xor(ss, 16);
    ss += __shfl_xor(ss, 32);
    if (lg == 0)
        out_cell[((size_t)b * W_ + w0 + wS) * Z_ + z] = __logf(ss);
    inv = 1.0f / ss;
}

// normalized P^T -> sP rows z. (R10 phase 6.)
static __device__ __forceinline__ void pt_write(unsigned char* sP, int wS, int zq,
                                                int fr, int lg,
                                                const float ex[4][4], float inv) {
    const int z = zq * 16 + fr;
#pragma unroll
    for (int mt = 0; mt < 4; ++mt) {
        int2 pk;
        pk.x = (f2bf(ex[mt][0] * inv) & 0xffff) | (f2bf(ex[mt][1] * inv) << 16);
        pk.y = (f2bf(ex[mt][2] * inv) & 0xffff) | (f2bf(ex[mt][3] * inv) << 16);
        *(int2*)(sP + swz(wS, z, mt * 2 + (lg >> 1)) + ((lg & 1) << 3)) = pk;
    }
}

// PV GEMM + direct float4-over-w stores. (R10 phases 7-8.)
static __device__ __forceinline__ void pv_store(const unsigned char* sP, const unsigned char* sA,
                                                int b, int w0, int mtp, int ntp, int fr, int lg,
                                                float* __restrict__ out_img) {
    f32x4 acc[4] = {};
#pragma unroll
    for (int w = 0; w < 4; ++w)
#pragma unroll
        for (int ks = 0; ks < 2; ++ks) {
            const bf16x8 a  = *(const bf16x8*)(sA + swz(w, mtp * 16 + fr, ks * 4 + lg));
            const bf16x8 bb = *(const bf16x8*)(sP + swz(w, ntp * 16 + fr, ks * 4 + lg));
            acc[w] = __builtin_amdgcn_mfma_f32_16x16x32_bf16(a, bb, acc[w], 0, 0, 0);
        }
#pragma unroll
    for (int r = 0; r < 4; ++r) {
        const int d  = mtp * 16 + lg * 4 + r;
        const int zc = ntp * 16 + fr;
        float4 o;
        o.x = acc[0][r];
        o.y = acc[1][r];
        o.z = acc[2][r];
        o.w = acc[3][r];
        *(float4*)(out_img + ((size_t)((b * D_ + d) * Z_) + zc) * W_ + w0) = o;
    }
}

// Two (b,w)-tiles per block, full LDS double-buffer, software-pipelined:
// tile1's global loads are issued before tile0's compute; tile1's LDS fill
// sits under tile0's PV-MFMA. Only the prologue exposes global latency.
__global__ __launch_bounds__(1024, 4)
void polar_fused2_kernel(const float* __restrict__ image,
                         const float* __restrict__ polar,
                         float* __restrict__ out_img,
                         float* __restrict__ out_cell) {
    __shared__ __align__(16) unsigned char sP0[4 * 8192];
    __shared__ __align__(16) unsigned char sA0[4 * 8192];
    __shared__ __align__(16) unsigned char sP1[4 * 8192];
    __shared__ __align__(16) unsigned char sA1[4 * 8192];   // 128 KB total

    const int t = threadIdx.x;
    // XCD-bijective swizzle: grid 512 (%8==0); each XCD gets 64 consecutive
    // block-pairs = 128 consecutive w-tiles (shared image/output lines).
    const int cpx = gridDim.x >> 3;
    const int logical = (blockIdx.x & 7) * cpx + (blockIdx.x >> 3);
    const int tile0 = logical << 1;          // even -> tile1 = tile0+1 has same b
    const int b   = tile0 >> 5;
    const int w0a = (tile0 & 31) << 2;
    const int w0b = w0a + 4;

    const int lane = t & 63, wv = t >> 6;
    const int fr = lane & 15, lg = lane >> 4;
    const int wS = wv >> 2, zq = wv & 3;     // same mapping serves S (wS,zq) and PV (mtp,ntp)

    Regs r0, r1;
    issue_loads(image, polar, b, w0a, t, r0);
    lds_write(sP0, sA0, t, r0);              // waitcnt tile0 loads
    issue_loads(image, polar, b, w0b, t, r1);// tile1 loads in flight across B1..B4
    __syncthreads();                         // B1: buf0 ready

    float ex0[4][4], inv0;
    s_phase(sP0, b, w0a, wS, zq, fr, lg, out_cell, ex0, inv0);
    __syncthreads();                         // B2: S reads of sP0 done
    pt_write(sP0, wS, zq, fr, lg, ex0, inv0);
    __syncthreads();                         // B3: P^T ready

    pv_store(sP0, sA0, b, w0a, wS, zq, fr, lg, out_img);
    lds_write(sP1, sA1, t, r1);              // fill buf1 under tile0's PV
    __syncthreads();                         // B4: buf1 ready (PV0 reads also done)

    float ex1[4][4], inv1;
    s_phase(sP1, b, w0b, wS, zq, fr, lg, out_cell, ex1, inv1);
    __syncthreads();                         // B5: S reads of sP1 done
    pt_write(sP1, wS, zq, fr, lg, ex1, inv1);
    __syncthreads();                         // B6: P^T ready
    pv_store(sP1, sA1, b, w0b, wS, zq, fr, lg, out_img);
}

extern "C" void kernel_launch(void* const* d_in, const int* in_sizes, int n_in,
                              void* d_out, int out_size, void* d_ws, size_t ws_size,
                              hipStream_t stream) {
    const float* image = (const float*)d_in[0];
    const float* polar = (const float*)d_in[1];
    float* out_img  = (float*)d_out;
    float* out_cell = out_img + (size_t)B_ * D_ * Z_ * W_;
    (void)d_ws; (void)ws_size;
    dim3 grid(B_ * (W_ / 4) / 2);   // 512 block-pairs
    polar_fused2_kernel<<<grid, 1024, 0, stream>>>(image, polar, out_img, out_cell);
}

// Round 13
// 56.541 us; speedup vs baseline: 1.0452x; 1.0452x over previous
//
#include <hip/hip_runtime.h>
#include <hip/hip_bf16.h>
#include <math.h>

// image: (B=32, D=64, H=64, W=128) f32
// polar_log_depths: (B=32, H=64, W=128, S=64) f32
// outputs: image_polar (B,D,Z=64,W) f32, cell_score (B,W,Z) f32, concat flat.
#define B_ 32
#define D_ 64
#define H_ 64
#define W_ 128
#define S_ 64
#define Z_ 64

typedef __attribute__((ext_vector_type(8))) short bf16x8;
typedef __attribute__((ext_vector_type(4))) float f32x4;

static __device__ __forceinline__ short f2bf(float f) {
    union { __hip_bfloat16 h; short s; } u;
    u.h = __float2bfloat16(f);
    return u.s;
}
static __device__ __forceinline__ float getc(const float4& v, int k) {
    switch (k) { case 0: return v.x; case 1: return v.y; case 2: return v.z; default: return v.w; }
}
// pack two float4 (8 consecutive f32) into a bf16x8 fragment
static __device__ __forceinline__ bf16x8 cvt8(const float4& a, const float4& b) {
    bf16x8 v;
    v[0] = f2bf(a.x); v[1] = f2bf(a.y); v[2] = f2bf(a.z); v[3] = f2bf(a.w);
    v[4] = f2bf(b.x); v[5] = f2bf(b.y); v[6] = f2bf(b.z); v[7] = f2bf(b.w);
    return v;
}

// Swizzled byte offset of a 16B column-octet slot in an 8KB [64 rows][128 B] plane.
static __device__ __forceinline__ int swz(int w, int row, int oct) {
    return w * 8192 + row * 128 + (((oct ^ row ^ w) & 7) << 4);
}

// Single-barrier fused kernel. Per (b, w-quad), 512 threads / 8 waves:
//   image -> LDS (bf16, transposed [d][h]) ............ staged early
//   polar -> REGISTERS (A-frags direct) -> S-MFMA ...... no LDS, no barrier
//   softmax in registers -> P^T -> LDS
//   ONE barrier
//   PV-MFMA -> direct float4-over-w stores (R10 geometry, clean WRITE)
__global__ __launch_bounds__(512, 4)
void polar_fused1b_kernel(const float* __restrict__ image,
                          const float* __restrict__ polar,
                          float* __restrict__ out_img,
                          float* __restrict__ out_cell) {
    __shared__ __align__(16) unsigned char sA[4 * 8192];   // image bf16 [w][d][h]
    __shared__ __align__(16) unsigned char sP[4 * 8192];   // P^T  bf16 [w][z][h]

    const int t = threadIdx.x;
    // XCD-bijective swizzle: grid 1024 (%8==0).
    const int cpx = gridDim.x >> 3;
    const int logical = (blockIdx.x & 7) * cpx + (blockIdx.x >> 3);
    const int b  = logical >> 5;
    const int w0 = (logical & 31) << 2;

    const int lane = t & 63, wv = t >> 6;
    const int fr = lane & 15, lg = lane >> 4;

    // ---- 1. image -> sA: thread owns 2 (d, h-quad) units of 64B contiguous ----
#pragma unroll
    for (int p = 0; p < 2; ++p) {
        const int u  = p * 512 + t;
        const int d  = u >> 4;
        const int h0 = (u & 15) << 2;
        float4 ir[4];
#pragma unroll
        for (int k = 0; k < 4; ++k)
            ir[k] = *(const float4*)(image + ((size_t)((b * D_ + d) * H_ + h0 + k)) * W_ + w0);
#pragma unroll
        for (int w = 0; w < 4; ++w) {
            int2 pk;
            pk.x = (f2bf(getc(ir[0], w)) & 0xffff) | (f2bf(getc(ir[1], w)) << 16);
            pk.y = (f2bf(getc(ir[2], w)) & 0xffff) | (f2bf(getc(ir[3], w)) << 16);
            *(int2*)(sA + swz(w, d, h0 >> 3) + ((h0 & 7) << 1)) = pk;
        }
    }

    // ---- 2. S phase, zero-LDS: wave = (wS, zh); lane covers z = zh*32+zt*16+fr ----
    const int wS = wv >> 1, zh = wv & 1;

    bf16x8 bw[2][2];   // [ks][zt] Wz^T fragments, built in registers
    float  invz[2];
#pragma unroll
    for (int zt = 0; zt < 2; ++zt) {
        const int z = zh * 32 + zt * 16 + fr;
        const float posf = (log2f(0.5f + 0.5f * (float)z) + 1.0f) * 10.5f;  // (63/6)
        int i0 = (int)floorf(posf);
        i0 = i0 < 0 ? 0 : (i0 > S_ - 1 ? S_ - 1 : i0);
        const int i1 = (i0 + 1 > S_ - 1) ? (S_ - 1) : (i0 + 1);
        const float wz = posf - (float)i0;
#pragma unroll
        for (int ks = 0; ks < 2; ++ks)
#pragma unroll
            for (int e = 0; e < 8; ++e) {
                const int s = ks * 32 + lg * 8 + e;
                const float v = (s == i0 ? 1.0f - wz : 0.0f) + (s == i1 ? wz : 0.0f);
                bw[ks][zt][e] = f2bf(v);
            }
    }

    // polar A-frags straight from global: lane (fr,lg) reads rows h=mt*16+fr,
    // s-slices lg*8 (+ks*32). 4-lane lg-groups form 64B-contiguous granules.
    const float* pb = polar + ((size_t)((b * H_ + fr) * W_) + (w0 + wS)) * S_ + lg * 8;

    f32x4 sacc[4][2] = {};   // [mt][zt]
#pragma unroll
    for (int mt = 0; mt < 4; ++mt) {
        const float* pm = pb + (size_t)mt * 16 * W_ * S_;
        const float4 c00 = *(const float4*)(pm);
        const float4 c01 = *(const float4*)(pm + 4);
        const float4 c10 = *(const float4*)(pm + 32);
        const float4 c11 = *(const float4*)(pm + 36);
        const bf16x8 a0 = cvt8(c00, c01);
        const bf16x8 a1 = cvt8(c10, c11);
        sacc[mt][0] = __builtin_amdgcn_mfma_f32_16x16x32_bf16(a0, bw[0][0], sacc[mt][0], 0, 0, 0);
        sacc[mt][0] = __builtin_amdgcn_mfma_f32_16x16x32_bf16(a1, bw[1][0], sacc[mt][0], 0, 0, 0);
        sacc[mt][1] = __builtin_amdgcn_mfma_f32_16x16x32_bf16(a0, bw[0][1], sacc[mt][1], 0, 0, 0);
        sacc[mt][1] = __builtin_amdgcn_mfma_f32_16x16x32_bf16(a1, bw[1][1], sacc[mt][1], 0, 0, 0);
    }

    // ---- 3. softmax over h in registers (no max-subtract; proven R8/R10) ----
#pragma unroll
    for (int zt = 0; zt < 2; ++zt) {
        float ss = 0.0f;
#pragma unroll
        for (int mt = 0; mt < 4; ++mt)
#pragma unroll
            for (int r = 0; r < 4; ++r) {
                const float e = __expf(sacc[mt][zt][r]);
                sacc[mt][zt][r] = e;
                ss += e;
            }
        ss += __shfl_xor(ss, 16);
        ss += __shfl_xor(ss, 32);
        if (lg == 0)
            out_cell[((size_t)b * W_ + w0 + wS) * Z_ + zh * 32 + zt * 16 + fr] = __logf(ss);
        invz[zt] = 1.0f / ss;
    }

    // ---- 4. P^T -> sP rows z (b64 packs of 4 h-contiguous bf16) ----
#pragma unroll
    for (int zt = 0; zt < 2; ++zt) {
        const int zrow = zh * 32 + zt * 16 + fr;
        const float inv = invz[zt];
#pragma unroll
        for (int mt = 0; mt < 4; ++mt) {
            int2 pk;
            pk.x = (f2bf(sacc[mt][zt][0] * inv) & 0xffff) | (f2bf(sacc[mt][zt][1] * inv) << 16);
            pk.y = (f2bf(sacc[mt][zt][2] * inv) & 0xffff) | (f2bf(sacc[mt][zt][3] * inv) << 16);
            *(int2*)(sP + swz(wS, zrow, mt * 2 + (lg >> 1)) + ((lg & 1) << 3)) = pk;
        }
    }
    __syncthreads();   // THE barrier: sA + sP ready

    // ---- 5. PV GEMM: wave (mtp,ntq) does 16d x 32z x 4w, K=64 ----
    const int mtp = wv >> 1, ntq = wv & 1;
    f32x4 acc[4][2] = {};   // [w][zz]
#pragma unroll
    for (int w = 0; w < 4; ++w)
#pragma unroll
        for (int ks = 0; ks < 2; ++ks) {
            const bf16x8 a = *(const bf16x8*)(sA + swz(w, mtp * 16 + fr, ks * 4 + lg));
#pragma unroll
            for (int zz = 0; zz < 2; ++zz) {
                const bf16x8 bb = *(const bf16x8*)(sP + swz(w, ntq * 32 + zz * 16 + fr, ks * 4 + lg));
                acc[w][zz] = __builtin_amdgcn_mfma_f32_16x16x32_bf16(a, bb, acc[w][zz], 0, 0, 0);
            }
        }

    // ---- 6. direct stores: one float4 over w per (d,z) — R10 geometry ----
#pragma unroll
    for (int zz = 0; zz < 2; ++zz)
#pragma unroll
        for (int r = 0; r < 4; ++r) {
            const int d = mtp * 16 + lg * 4 + r;
            const int z = ntq * 32 + zz * 16 + fr;
            float4 o;
            o.x = acc[0][zz][r];
            o.y = acc[1][zz][r];
            o.z = acc[2][zz][r];
            o.w = acc[3][zz][r];
            *(float4*)(out_img + ((size_t)((b * D_ + d) * Z_) + z) * W_ + w0) = o;
        }
}

extern "C" void kernel_launch(void* const* d_in, const int* in_sizes, int n_in,
                              void* d_out, int out_size, void* d_ws, size_t ws_size,
                              hipStream_t stream) {
    const float* image = (const float*)d_in[0];
    const float* polar = (const float*)d_in[1];
    float* out_img  = (float*)d_out;
    float* out_cell = out_img + (size_t)B_ * D_ * Z_ * W_;
    (void)d_ws; (void)ws_size;
    dim3 grid(B_ * (W_ / 4));   // 1024 blocks
    polar_fused1b_kernel<<<grid, 512, 0, stream>>>(image, polar, out_img, out_cell);
}